// Round 4
// baseline (283.270 us; speedup 1.0000x reference)
//
#include <hip/hip_runtime.h>
#include <hip/hip_bf16.h>
#include <cstddef>
#include <cstdint>

#define Bv 4
#define Nv 1024
#define DM 512
#define Hh 8
#define DHv 64
#define TOKc 4096

typedef __attribute__((ext_vector_type(4))) float f32x4;
typedef __attribute__((ext_vector_type(8))) short s16x8;

__device__ __forceinline__ uint32_t f2bf_bits(float f) {
    uint32_t x = __float_as_uint(f);
    return (x + 0x7FFFu + ((x >> 16) & 1u)) >> 16;
}
__device__ __forceinline__ short f2bf(float f) { return (short)f2bf_bits(f); }
__device__ __forceinline__ float bf2f(short s) {
    return __uint_as_float(((uint32_t)(uint16_t)s) << 16);
}

__device__ __forceinline__ void g2lds16(const void* g, void* l) {
    __builtin_amdgcn_global_load_lds(
        (const __attribute__((address_space(1))) void*)g,
        (__attribute__((address_space(3))) void*)l, 16, 0, 0);
}

// ---------------------------------------------------------------------------
// all 4 weight tensors -> bf16, one launch
// ---------------------------------------------------------------------------
__global__ __launch_bounds__(256) void conv_all(
    const float* __restrict__ W0, const float* __restrict__ W1,
    const float* __restrict__ W2, const float* __restrict__ W3,
    short* __restrict__ D0, short* __restrict__ D1,
    short* __restrict__ D2, short* __restrict__ D3)
{
    int bid = blockIdx.x;
    const float* s; short* d; int base;
    if (bid < 768)       { s = W0; d = D0; base = bid * 1024; }
    else if (bid < 1024) { s = W1; d = D1; base = (bid - 768) * 1024; }
    else if (bid < 2048) { s = W2; d = D2; base = (bid - 1024) * 1024; }
    else                 { s = W3; d = D3; base = (bid - 2048) * 1024; }
    int i = base + threadIdx.x * 4;
    float4 v = *(const float4*)&s[i];
    short4 o = { f2bf(v.x), f2bf(v.y), f2bf(v.z), f2bf(v.w) };
    *(short4*)&d[i] = o;
}

// ---------------------------------------------------------------------------
// pack bias = new_mask - gamma*D (lo bf16) and mask (hi bf16) into u32
// ---------------------------------------------------------------------------
__global__ __launch_bounds__(256) void prep_bm(
    const float* __restrict__ Dm, const float* __restrict__ nm,
    const float* __restrict__ mk, const float* __restrict__ gamma,
    uint32_t* __restrict__ out)
{
    int i = (blockIdx.x * 256 + threadIdx.x) * 4;
    float g = gamma[0];
    float4 d = *(const float4*)&Dm[i];
    float4 n = *(const float4*)&nm[i];
    float4 m = *(const float4*)&mk[i];
    uint4 o;
    o.x = f2bf_bits(n.x - g * d.x) | (f2bf_bits(m.x) << 16);
    o.y = f2bf_bits(n.y - g * d.y) | (f2bf_bits(m.y) << 16);
    o.z = f2bf_bits(n.z - g * d.z) | (f2bf_bits(m.z) << 16);
    o.w = f2bf_bits(n.w - g * d.w) | (f2bf_bits(m.w) << 16);
    *(uint4*)&out[i] = o;
}

// ---------------------------------------------------------------------------
// LayerNorm -> bf16 out
// ---------------------------------------------------------------------------
__global__ __launch_bounds__(256) void ln_kernel(
    const float* __restrict__ X, const float* __restrict__ g,
    const float* __restrict__ bb, short* __restrict__ Y)
{
    __shared__ float red[8];
    int row = blockIdx.x, tid = threadIdx.x;
    const float* x = X + (size_t)row * DM;
    float v0 = x[tid], v1 = x[tid + 256];
    float s = v0 + v1, ss = v0 * v0 + v1 * v1;
#pragma unroll
    for (int o = 32; o > 0; o >>= 1) {
        s += __shfl_xor(s, o);
        ss += __shfl_xor(ss, o);
    }
    int lane = tid & 63, wid = tid >> 6;
    if (lane == 0) { red[wid] = s; red[4 + wid] = ss; }
    __syncthreads();
    float S = red[0] + red[1] + red[2] + red[3];
    float SS = red[4] + red[5] + red[6] + red[7];
    float mean = S * (1.f / DM);
    float var = SS * (1.f / DM) - mean * mean;
    float rstd = rsqrtf(var + 1e-5f);
    short* y = Y + (size_t)row * DM;
    y[tid]       = f2bf((v0 - mean) * rstd * g[tid]       + bb[tid]);
    y[tid + 256] = f2bf((v1 - mean) * rstd * g[tid + 256] + bb[tid + 256]);
}

// ---------------------------------------------------------------------------
// bf16 MFMA NT GEMM (unchanged from R3)
// ---------------------------------------------------------------------------
template <int EPI, int BM, int BN>
__global__ __launch_bounds__(256) void gemm_bf16(
    const short* __restrict__ A, const short* __restrict__ Bw,
    const float* __restrict__ bias, const float* __restrict__ resid,
    void* __restrict__ C0, short* __restrict__ C2, short* __restrict__ C3,
    int M, int N, int Ks, int Kst)
{
    constexpr int FI = BM / 32, FJ = BN / 32;
    __shared__ short As[BM * 32];
    __shared__ short Bs[BN * 32];
    int tid = threadIdx.x;
    int lane = tid & 63, wave = tid >> 6;
    int bm = blockIdx.y * BM, bn = blockIdx.x * BN;
    int wm = (wave >> 1) * (BM / 2), wn = (wave & 1) * (BN / 2);
    int n_lo = lane & 15, quad = lane >> 4;

    f32x4 acc[FI][FJ] = {};

    int koff = (EPI == 4) ? blockIdx.z * Ks : 0;
    int lrow = lane >> 2, lchunk = (lane & 3) * 8;
    const short* Ag = A + (size_t)(bm + wave * (BM / 4) + lrow) * Kst + koff + lchunk;
    const short* Bg = Bw + (size_t)(bn + wave * (BN / 4) + lrow) * Kst + koff + lchunk;

    for (int k0 = 0; k0 < Ks; k0 += 32) {
        __syncthreads();
#pragma unroll
        for (int r = 0; r < BM / 64; r++)
            g2lds16(Ag + (size_t)r * 16 * Kst + k0, &As[(wave * (BM / 4) + r * 16) * 32]);
#pragma unroll
        for (int r = 0; r < BN / 64; r++)
            g2lds16(Bg + (size_t)r * 16 * Kst + k0, &Bs[(wave * (BN / 4) + r * 16) * 32]);
        __syncthreads();
        s16x8 af[FI], bf[FJ];
#pragma unroll
        for (int i = 0; i < FI; i++)
            af[i] = *(const s16x8*)&As[(wm + i * 16 + n_lo) * 32 + quad * 8];
#pragma unroll
        for (int j = 0; j < FJ; j++)
            bf[j] = *(const s16x8*)&Bs[(wn + j * 16 + n_lo) * 32 + quad * 8];
#pragma unroll
        for (int i = 0; i < FI; i++)
#pragma unroll
            for (int j = 0; j < FJ; j++)
                acc[i][j] = __builtin_amdgcn_mfma_f32_16x16x32_bf16(
                    af[i], bf[j], acc[i][j], 0, 0, 0);
    }

#pragma unroll
    for (int i = 0; i < FI; i++) {
#pragma unroll
        for (int j = 0; j < FJ; j++) {
            int col = bn + wn + j * 16 + n_lo;
#pragma unroll
            for (int r = 0; r < 4; r++) {
                int m = bm + wm + i * 16 + quad * 4 + r;
                float v = acc[i][j][r];
                if (EPI == 0) {
                    v += bias[col];
                    int hh = col / 192;
                    int rr = col - hh * 192;
                    int part = rr >> 6, dd = rr & 63;
                    int bI = m >> 10, nI = m & 1023;
                    if (part == 0)
                        ((short*)C0)[((size_t)((bI * Hh + hh) * DHv + dd)) * Nv + nI] = f2bf(v);
                    else if (part == 1)
                        C2[((size_t)((bI * Hh + hh) * Nv + nI)) * DHv + dd] = f2bf(v);
                    else
                        C3[((size_t)((bI * Hh + hh) * Nv + nI)) * DHv + dd] = f2bf(v);
                } else if (EPI == 1) {
                    ((float*)C0)[(size_t)m * N + col] = v + resid[(size_t)m * N + col];
                } else if (EPI == 2) {
                    v += bias[col];
                    ((short*)C0)[(size_t)m * N + col] = f2bf(v > 0.f ? v : 0.f);
                } else {
                    ((short*)C0)[(size_t)blockIdx.z * M * N + (size_t)m * N + col] = f2bf(v);
                }
            }
        }
    }
}

// ---------------------------------------------------------------------------
// out = P0 + P1 + bias + resid   (MLP2 split-K combine)
// ---------------------------------------------------------------------------
__global__ __launch_bounds__(256) void combine_mlp2(
    const short* __restrict__ P, const float* __restrict__ bias,
    const float* __restrict__ resid, float* __restrict__ out)
{
    int i = (blockIdx.x * 256 + threadIdx.x) * 4;
    float4 rz = *(const float4*)&resid[i];
    float4 bz = *(const float4*)&bias[i & 511];
    short4 p0 = *(const short4*)&P[i];
    short4 p1 = *(const short4*)&P[i + 2097152];
    float4 o;
    o.x = bf2f(p0.x) + bf2f(p1.x) + bz.x + rz.x;
    o.y = bf2f(p0.y) + bf2f(p1.y) + bz.y + rz.y;
    o.z = bf2f(p0.z) + bf2f(p1.z) + bz.z + rz.z;
    o.w = bf2f(p0.w) + bf2f(p1.w) + bz.w + rz.w;
    *(float4*)&out[i] = o;
}

// ---------------------------------------------------------------------------
// Flash attention, split-K, DEINTERLEAVED:
// phase A: all scores for the wave's 256-key strip (MFMA + bias), regs
// phase B: one batched max/exp/sum (32 shuffle ops total)
// phase C: P -> padded LDS -> PV MFMAs
// merge: (m,l,O) across the 4 waves via LDS
// ---------------------------------------------------------------------------
__global__ __launch_bounds__(256) void attn_mfma(
    const short* __restrict__ Q, const short* __restrict__ K,
    const short* __restrict__ Vt, const uint32_t* __restrict__ Bm,
    short* __restrict__ attn_l)
{
    __shared__ short Pl[4][16][264];   // stride 264 shorts = 528 B (16B-aligned, bank-spread)
    __shared__ float Osh[4][16][68];
    __shared__ float Msh[4][16];
    __shared__ float Lsh[4][16];

    int tid = threadIdx.x, lane = tid & 63, wave = tid >> 6;
    int n_lo = lane & 15, quad = lane >> 4;
    int q0 = blockIdx.x * 16;
    int b = blockIdx.y >> 3, h = blockIdx.y & 7;
    int kbase = wave * 256;

    const short* Qp = Q + ((size_t)((b * Hh + h) * Nv + q0)) * DHv;
    const short* Kp = K + ((size_t)((b * Hh + h) * Nv + kbase)) * DHv;
    const short* Vp = Vt + ((size_t)((b * Hh + h) * DHv)) * Nv;
    const uint32_t* Bp = Bm + ((size_t)(b * Nv + q0)) * Nv + kbase;

    s16x8 a0 = *(const s16x8*)&Qp[n_lo * DHv + quad * 8];
    s16x8 a1 = *(const s16x8*)&Qp[n_lo * DHv + 32 + quad * 8];

    float sc[64];      // scores: sc[it*8+i] = key it*32+n_lo, row quad*4+i
    uint32_t mkp[32];  // packed masks: lo16 = mask(key n_lo), hi16 = mask(key 16+n_lo)

    // ---- phase A: scores ----
#pragma unroll
    for (int it = 0; it < 8; ++it) {
        const short* kb = Kp + (size_t)it * 32 * DHv;
        s16x8 k0a = *(const s16x8*)&kb[n_lo * DHv + quad * 8];
        s16x8 k0b = *(const s16x8*)&kb[n_lo * DHv + 32 + quad * 8];
        s16x8 k1a = *(const s16x8*)&kb[(16 + n_lo) * DHv + quad * 8];
        s16x8 k1b = *(const s16x8*)&kb[(16 + n_lo) * DHv + 32 + quad * 8];
        f32x4 z = {0.f, 0.f, 0.f, 0.f};
        f32x4 s0 = __builtin_amdgcn_mfma_f32_16x16x32_bf16(
            a1, k0b, __builtin_amdgcn_mfma_f32_16x16x32_bf16(a0, k0a, z, 0, 0, 0), 0, 0, 0);
        f32x4 s1 = __builtin_amdgcn_mfma_f32_16x16x32_bf16(
            a1, k1b, __builtin_amdgcn_mfma_f32_16x16x32_bf16(a0, k1a, z, 0, 0, 0), 0, 0, 0);
#pragma unroll
        for (int i = 0; i < 4; i++) {
            uint32_t u0 = Bp[(size_t)(quad * 4 + i) * Nv + it * 32 + n_lo];
            uint32_t u1 = Bp[(size_t)(quad * 4 + i) * Nv + it * 32 + 16 + n_lo];
            sc[it * 8 + i]     = s0[i] * 0.125f + __uint_as_float(u0 << 16);
            sc[it * 8 + 4 + i] = s1[i] * 0.125f + __uint_as_float(u1 << 16);
            mkp[it * 4 + i] = (u0 >> 16) | (u1 & 0xFFFF0000u);
        }
    }

    // ---- phase B: batched softmax stats ----
    float m4[4], l4[4];
#pragma unroll
    for (int i = 0; i < 4; i++) {
        float mx = sc[i];
#pragma unroll
        for (int it = 0; it < 8; it++) {
            mx = fmaxf(mx, sc[it * 8 + i]);
            mx = fmaxf(mx, sc[it * 8 + 4 + i]);
        }
#pragma unroll
        for (int off = 1; off < 16; off <<= 1) mx = fmaxf(mx, __shfl_xor(mx, off));
        m4[i] = mx;
        float s = 0.f;
#pragma unroll
        for (int it = 0; it < 8; it++) {
            float e0 = __expf(sc[it * 8 + i] - mx);
            float e1 = __expf(sc[it * 8 + 4 + i] - mx);
            sc[it * 8 + i] = e0;
            sc[it * 8 + 4 + i] = e1;
            s += e0 + e1;
        }
#pragma unroll
        for (int off = 1; off < 16; off <<= 1) s += __shfl_xor(s, off);
        l4[i] = s;
    }

    // ---- phase C: P (masked) -> LDS, then PV ----
    short* Pw = &Pl[wave][0][0];
#pragma unroll
    for (int it = 0; it < 8; it++)
#pragma unroll
        for (int i = 0; i < 4; i++) {
            int row = quad * 4 + i;
            float mk0 = __uint_as_float(mkp[it * 4 + i] << 16);
            float mk1 = __uint_as_float(mkp[it * 4 + i] & 0xFFFF0000u);
            Pw[row * 264 + it * 32 + n_lo]      = f2bf(sc[it * 8 + i] * mk0);
            Pw[row * 264 + it * 32 + 16 + n_lo] = f2bf(sc[it * 8 + 4 + i] * mk1);
        }

    f32x4 O[4] = {};
#pragma unroll
    for (int c = 0; c < 8; c++) {
        s16x8 pa = *(const s16x8*)&Pw[n_lo * 264 + c * 32 + quad * 8];
#pragma unroll
        for (int t = 0; t < 4; t++) {
            s16x8 vb = *(const s16x8*)&Vp[(size_t)(t * 16 + n_lo) * Nv + kbase + c * 32 + quad * 8];
            O[t] = __builtin_amdgcn_mfma_f32_16x16x32_bf16(pa, vb, O[t], 0, 0, 0);
        }
    }

    // ---- merge 4 wave-partials ----
    if (n_lo == 0) {
#pragma unroll
        for (int i = 0; i < 4; i++) Msh[wave][quad * 4 + i] = m4[i];
    }
    __syncthreads();
    float scale[4];
#pragma unroll
    for (int i = 0; i < 4; i++) {
        int r = quad * 4 + i;
        float ms = fmaxf(fmaxf(Msh[0][r], Msh[1][r]), fmaxf(Msh[2][r], Msh[3][r]));
        scale[i] = __expf(m4[i] - ms);
    }
    if (n_lo == 0) {
#pragma unroll
        for (int i = 0; i < 4; i++) Lsh[wave][quad * 4 + i] = l4[i] * scale[i];
    }
#pragma unroll
    for (int t = 0; t < 4; t++)
#pragma unroll
        for (int i = 0; i < 4; i++)
            Osh[wave][quad * 4 + i][t * 16 + n_lo] = O[t][i] * scale[i];
    __syncthreads();

    int col = tid & 63, rb = (tid >> 6) * 4;
#pragma unroll
    for (int r = 0; r < 4; r++) {
        int row = rb + r;
        float s = Osh[0][row][col] + Osh[1][row][col] + Osh[2][row][col] + Osh[3][row][col];
        float lt = Lsh[0][row] + Lsh[1][row] + Lsh[2][row] + Lsh[3][row];
        float o = s / lt;
        o = o > 0.f ? o : 0.01f * o;
        attn_l[((size_t)(b * Nv + q0 + row)) * DM + h * DHv + col] = f2bf(o);
    }
}

// ---------------------------------------------------------------------------
extern "C" void kernel_launch(void* const* d_in, const int* in_sizes, int n_in,
                              void* d_out, int out_size, void* d_ws, size_t ws_size,
                              hipStream_t stream)
{
    const float* Z     = (const float*)d_in[0];
    const float* D     = (const float*)d_in[1];
    const float* nmsk  = (const float*)d_in[2];
    const float* msk   = (const float*)d_in[3];
    const float* Wqkv  = (const float*)d_in[4];
    const float* bqkv  = (const float*)d_in[5];
    const float* Wo    = (const float*)d_in[6];
    const float* g1    = (const float*)d_in[7];
    const float* b1    = (const float*)d_in[8];
    const float* g2    = (const float*)d_in[9];
    const float* b2    = (const float*)d_in[10];
    const float* Wp1   = (const float*)d_in[11];
    const float* bp1   = (const float*)d_in[12];
    const float* Wp2   = (const float*)d_in[13];
    const float* bp2   = (const float*)d_in[14];
    const float* gamma = (const float*)d_in[15];
    float* out = (float*)d_out;
    char* w = (char*)d_ws;

    const size_t MB = 1048576;
    short*    WqkvB = (short*)(w);
    short*    WoB   = (short*)(w + 1572864);
    short*    Wp1B  = (short*)(w + 2 * MB);
    short*    Wp2B  = (short*)(w + 4 * MB);
    float*    Z2    = (float*)(w + 6 * MB);
    uint32_t* Bm    = (uint32_t*)(w + 14 * MB);
    short*    Zn    = (short*)(w + 30 * MB);
    short*    Qb    = (short*)(w + 34 * MB);
    short*    Kb    = (short*)(w + 38 * MB);
    short*    VtB   = (short*)(w + 42 * MB);
    short*    AtnL  = (short*)(w + 30 * MB);
    short*    Zn2   = (short*)(w + 14 * MB);
    short*    Hb    = (short*)(w + 18 * MB);
    short*    Pp    = (short*)(w + 34 * MB);

    conv_all<<<3072, 256, 0, stream>>>(Wqkv, Wo, Wp1, Wp2, WqkvB, WoB, Wp1B, Wp2B);
    prep_bm<<<4096, 256, 0, stream>>>(D, nmsk, msk, gamma, Bm);
    ln_kernel<<<TOKc, 256, 0, stream>>>(Z, g1, b1, Zn);
    gemm_bf16<0, 128, 64><<<dim3(24, 32), 256, 0, stream>>>(
        Zn, WqkvB, bqkv, nullptr, VtB, Qb, Kb, TOKc, 1536, 512, 512);
    attn_mfma<<<dim3(64, 32), 256, 0, stream>>>(Qb, Kb, VtB, Bm, AtnL);
    gemm_bf16<1, 64, 64><<<dim3(8, 64), 256, 0, stream>>>(
        AtnL, WoB, nullptr, Z, Z2, nullptr, nullptr, TOKc, 512, 512, 512);
    ln_kernel<<<TOKc, 256, 0, stream>>>(Z2, g2, b2, Zn2);
    gemm_bf16<2, 128, 64><<<dim3(32, 32), 256, 0, stream>>>(
        Zn2, Wp1B, bp1, nullptr, Hb, nullptr, nullptr, TOKc, 2048, 512, 512);
    gemm_bf16<4, 128, 64><<<dim3(8, 32, 2), 256, 0, stream>>>(
        Hb, Wp2B, nullptr, nullptr, Pp, nullptr, nullptr, TOKc, 512, 1024, 2048);
    combine_mlp2<<<2048, 256, 0, stream>>>(Pp, bp2, Z2, out);
}